// Round 1
// baseline (36.223 us; speedup 1.0000x reference)
//
#include <hip/hip_runtime.h>
#include <math.h>

// out[0][i]   = (floor((x[i]/max(x))*255) == t) ? weight[0][i] : 0
// out[r>0][*] = 0
//
// Memory-bound on the 128 MiB output zero-fill. One fused kernel:
//  - all blocks: grid-stride float4 zero-fill of rows 1..out_f-1
//  - block 0:    block-wide max reduce over x, then writes row 0
__global__ __launch_bounds__(256) void TemporalEncoder_69707319214330_kernel(
    const float* __restrict__ x,
    const float* __restrict__ w,
    const int* __restrict__ t_ptr,
    float* __restrict__ out,
    int in_f,
    long long total)
{
    const int tid = threadIdx.x;

    // ---- zero-fill everything past row 0, vectorized 16 B/lane ----
    const long long row0_vec  = in_f >> 2;     // float4 count of row 0
    const long long total_vec = total >> 2;
    float4* out4 = reinterpret_cast<float4*>(out);
    const float4 z = make_float4(0.f, 0.f, 0.f, 0.f);
    for (long long i = row0_vec + (long long)blockIdx.x * blockDim.x + tid;
         i < total_vec;
         i += (long long)gridDim.x * blockDim.x) {
        out4[i] = z;
    }

    // ---- block 0: max(x) then row-0 mask*weight ----
    if (blockIdx.x == 0) {
        float m = -INFINITY;
        for (int i = tid; i < in_f; i += 256) m = fmaxf(m, x[i]);
        // wave64 shuffle reduce
        for (int off = 32; off > 0; off >>= 1)
            m = fmaxf(m, __shfl_down(m, off, 64));
        __shared__ float smax[4];
        if ((tid & 63) == 0) smax[tid >> 6] = m;
        __syncthreads();
        const float mx = fmaxf(fmaxf(smax[0], smax[1]), fmaxf(smax[2], smax[3]));
        const int t = *t_ptr;
        for (int i = tid; i < in_f; i += 256) {
            // exact reference op order: (x / max) * 255, floor, int compare
            const float xn = (x[i] / mx) * 255.0f;
            const int   xq = (int)floorf(xn);
            out[i] = (xq == t) ? w[i] : 0.0f;
        }
    }
}

extern "C" void kernel_launch(void* const* d_in, const int* in_sizes, int n_in,
                              void* d_out, int out_size, void* d_ws, size_t ws_size,
                              hipStream_t stream) {
    const float* x = (const float*)d_in[0];
    const float* w = (const float*)d_in[1];
    const int*   t = (const int*)d_in[2];
    float* out = (float*)d_out;

    const int in_f = in_sizes[0];          // 8192 (x is (1, in_f))
    const long long total = (long long)out_size;  // 4096 * 8192

    // memory-bound: cap grid ~2048 blocks, grid-stride the rest (G11)
    TemporalEncoder_69707319214330_kernel<<<dim3(2048), dim3(256), 0, stream>>>(
        x, w, t, out, in_f, total);
}

// Round 2
// 26.883 us; speedup vs baseline: 1.3474x; 1.3474x over previous
//
#include <hip/hip_runtime.h>
#include <math.h>

// out[0][i]   = (floor((x[i]/max(x))*255) == t) ? weight[0][i] : 0
// out[r>0][*] = 0
//
// Strategy: rows 1..out_f-1 are a pure 128 MiB zero-fill -> hipMemsetAsync
// (rocclr's fillBufferAligned sustains ~7 TB/s write-only on this chip,
// measured in round-1 rocprof; our hand fill loop only hit ~4 TB/s).
// Row 0 (max-reduce over 8192 floats + mask*weight) is one tiny
// latency-bound block (~64 KB total traffic).
__global__ __launch_bounds__(1024) void TemporalEncoder_69707319214330_row0(
    const float* __restrict__ x,
    const float* __restrict__ w,
    const int* __restrict__ t_ptr,
    float* __restrict__ out,
    int in_f)
{
    const int tid = threadIdx.x;
    const int nvec = in_f >> 2;                 // float4 count (8192 -> 2048)
    const float4* x4 = reinterpret_cast<const float4*>(x);

    // ---- max(x), vectorized ----
    float m = -INFINITY;
    for (int i = tid; i < nvec; i += 1024) {
        const float4 v = x4[i];
        m = fmaxf(m, fmaxf(fmaxf(v.x, v.y), fmaxf(v.z, v.w)));
    }
    for (int i = (nvec << 2) + tid; i < in_f; i += 1024)  // scalar tail (unused at 8192)
        m = fmaxf(m, x[i]);

    // wave64 shuffle reduce, then cross-wave via LDS
    for (int off = 32; off > 0; off >>= 1)
        m = fmaxf(m, __shfl_down(m, off, 64));
    __shared__ float smax[16];
    if ((tid & 63) == 0) smax[tid >> 6] = m;
    __syncthreads();
    float mx = -INFINITY;
    #pragma unroll
    for (int wv = 0; wv < 16; ++wv) mx = fmaxf(mx, smax[wv]);

    // ---- row 0: exact reference op order (x/max)*255 -> floor -> int == t ----
    const int t = *t_ptr;
    const float4* w4 = reinterpret_cast<const float4*>(w);
    float4* out4 = reinterpret_cast<float4*>(out);
    for (int i = tid; i < nvec; i += 1024) {
        const float4 xv = x4[i];
        const float4 wv = w4[i];
        float4 o;
        o.x = ((int)floorf((xv.x / mx) * 255.0f) == t) ? wv.x : 0.0f;
        o.y = ((int)floorf((xv.y / mx) * 255.0f) == t) ? wv.y : 0.0f;
        o.z = ((int)floorf((xv.z / mx) * 255.0f) == t) ? wv.z : 0.0f;
        o.w = ((int)floorf((xv.w / mx) * 255.0f) == t) ? wv.w : 0.0f;
        out4[i] = o;
    }
    for (int i = (nvec << 2) + tid; i < in_f; i += 1024)
        out[i] = ((int)floorf((x[i] / mx) * 255.0f) == t) ? w[i] : 0.0f;
}

extern "C" void kernel_launch(void* const* d_in, const int* in_sizes, int n_in,
                              void* d_out, int out_size, void* d_ws, size_t ws_size,
                              hipStream_t stream) {
    const float* x = (const float*)d_in[0];
    const float* w = (const float*)d_in[1];
    const int*   t = (const int*)d_in[2];
    float* out = (float*)d_out;

    const int in_f = in_sizes[0];                 // 8192
    const long long total = (long long)out_size;  // 4096 * 8192

    // Bulk zero of rows 1..end via the runtime's tuned fill kernel (~7 TB/s).
    // Offset in_f floats = 32 KB — alignment preserved. Async, capture-safe.
    hipMemsetAsync(out + in_f, 0, (size_t)(total - in_f) * sizeof(float), stream);

    // Row 0: one block, latency-bound.
    TemporalEncoder_69707319214330_row0<<<1, 1024, 0, stream>>>(x, w, t, out, in_f);
}